// Round 1
// baseline (291.291 us; speedup 1.0000x reference)
//
#include <hip/hip_runtime.h>
#include <hip/hip_bf16.h>

// Problem constants
#define BATCH 16
#define CIN 8
#define COUT 8
#define HH 512
#define WW 512
#define KK 3
constexpr int TPX = 4;                       // pixels per thread along h
constexpr float EPS = 1e-5f;
constexpr float NPC = (float)BATCH * HH * WW; // per-channel element count

// MODE 0: conv -> bf16 ws + stats atomics
// MODE 1: conv -> stats atomics only (no ws write)
// MODE 2: conv recompute -> normalize -> fp32 out (reads stats)
template <int MODE>
__global__ __launch_bounds__(256, 4)
void conv_kernel(const float* __restrict__ x,
                 const float* __restrict__ lin_w,
                 const float* __restrict__ gamma,
                 const float* __restrict__ beta,
                 __hip_bfloat16* __restrict__ ws_y,
                 float* __restrict__ stats,
                 float* __restrict__ out) {
    const int w  = blockIdx.x * 256 + threadIdx.x;   // 0..511
    const int h0 = blockIdx.y * TPX;                  // 0..508
    const int b  = blockIdx.z;

    float acc[TPX][COUT];
#pragma unroll
    for (int px = 0; px < TPX; ++px)
#pragma unroll
        for (int oc = 0; oc < COUT; ++oc) acc[px][oc] = 0.f;

    const float* xb = x + (size_t)b * CIN * HH * WW;
    const int wm = max(w - 1, 0), wp = min(w + 1, WW - 1);
    const bool wl = (w >= 1), wr = (w <= WW - 2);

    for (int ic = 0; ic < CIN; ++ic) {
        const float* xc = xb + (size_t)ic * HH * WW;
        float xv[TPX + 2][3];
#pragma unroll
        for (int r = 0; r < TPX + 2; ++r) {
            const int hraw = h0 - 1 + r;
            const int hcl = min(max(hraw, 0), HH - 1);
            const bool vr = (hraw >= 0) && (hraw < HH);
            const float* xr = xc + (size_t)hcl * WW;
            float a0 = xr[wm], a1 = xr[w], a2 = xr[wp];
            xv[r][0] = (vr && wl) ? a0 : 0.f;
            xv[r][1] = vr ? a1 : 0.f;
            xv[r][2] = (vr && wr) ? a2 : 0.f;
        }
#pragma unroll
        for (int kh = 0; kh < KK; ++kh) {
#pragma unroll
            for (int kw = 0; kw < KK; ++kw) {
                const int p = kh * KK + kw;
#pragma unroll
                for (int px = 0; px < TPX; ++px) {
                    const float xval = xv[kh + px][kw];
#pragma unroll
                    for (int oc = 0; oc < COUT; ++oc) {
                        // uniform address -> s_load; SGPR operand in v_fmac
                        acc[px][oc] = fmaf(xval, lin_w[(ic * COUT + oc) * 9 + p],
                                           acc[px][oc]);
                    }
                }
            }
        }
    }

    if (MODE == 0 || MODE == 1) {
        // per-thread channel sums
        float s[COUT], q[COUT];
#pragma unroll
        for (int oc = 0; oc < COUT; ++oc) {
            float ss = 0.f, qq = 0.f;
#pragma unroll
            for (int px = 0; px < TPX; ++px) {
                ss += acc[px][oc];
                qq = fmaf(acc[px][oc], acc[px][oc], qq);
            }
            s[oc] = ss; q[oc] = qq;
        }
        // wave (64-lane) reduce
#pragma unroll
        for (int off = 32; off > 0; off >>= 1) {
#pragma unroll
            for (int oc = 0; oc < COUT; ++oc) {
                s[oc] += __shfl_down(s[oc], off);
                q[oc] += __shfl_down(q[oc], off);
            }
        }
        __shared__ float reds[4][2 * COUT];
        const int lane = threadIdx.x & 63, wv = threadIdx.x >> 6;
        if (lane == 0) {
#pragma unroll
            for (int oc = 0; oc < COUT; ++oc) {
                reds[wv][oc] = s[oc];
                reds[wv][COUT + oc] = q[oc];
            }
        }
        __syncthreads();
        if (threadIdx.x < 2 * COUT) {
            float v = reds[0][threadIdx.x] + reds[1][threadIdx.x] +
                      reds[2][threadIdx.x] + reds[3][threadIdx.x];
            atomicAdd(&stats[threadIdx.x], v);
        }
        if (MODE == 0) {
#pragma unroll
            for (int oc = 0; oc < COUT; ++oc)
#pragma unroll
                for (int px = 0; px < TPX; ++px) {
                    size_t oidx = (((size_t)(b * COUT + oc)) * HH + (h0 + px)) * WW + w;
                    ws_y[oidx] = __float2bfloat16(acc[px][oc]);
                }
        }
    } else { // MODE 2: normalize + relu + write
#pragma unroll
        for (int oc = 0; oc < COUT; ++oc) {
            const float mean = stats[oc] * (1.f / NPC);
            const float var  = stats[COUT + oc] * (1.f / NPC) - mean * mean;
            const float rstd = rsqrtf(var + EPS);
            const float sc = gamma[oc] * rstd;
            const float sh = fmaf(-mean, sc, beta[oc]);
#pragma unroll
            for (int px = 0; px < TPX; ++px) {
                size_t oidx = (((size_t)(b * COUT + oc)) * HH + (h0 + px)) * WW + w;
                out[oidx] = fmaxf(fmaf(acc[px][oc], sc, sh), 0.f);
            }
        }
    }
}

// BN+ReLU from bf16 ws, 8 elements/thread
__global__ __launch_bounds__(256)
void bn_kernel(const __hip_bfloat16* __restrict__ ws_y,
               const float* __restrict__ stats,
               const float* __restrict__ gamma,
               const float* __restrict__ beta,
               float* __restrict__ out) {
    const size_t i8 = ((size_t)blockIdx.x * 256 + threadIdx.x) * 8;
    const int oc = (int)((i8 >> 18) & 7);  // HH*WW = 2^18
    const float mean = stats[oc] * (1.f / NPC);
    const float var  = stats[COUT + oc] * (1.f / NPC) - mean * mean;
    const float rstd = rsqrtf(var + EPS);
    const float sc = gamma[oc] * rstd;
    const float sh = fmaf(-mean, sc, beta[oc]);

    const uint4 u = *(const uint4*)((const char*)ws_y + i8 * 2);
    float v[8];
    v[0] = __uint_as_float(u.x << 16);
    v[1] = __uint_as_float(u.x & 0xffff0000u);
    v[2] = __uint_as_float(u.y << 16);
    v[3] = __uint_as_float(u.y & 0xffff0000u);
    v[4] = __uint_as_float(u.z << 16);
    v[5] = __uint_as_float(u.z & 0xffff0000u);
    v[6] = __uint_as_float(u.w << 16);
    v[7] = __uint_as_float(u.w & 0xffff0000u);
    float4 o0, o1;
    o0.x = fmaxf(fmaf(v[0], sc, sh), 0.f);
    o0.y = fmaxf(fmaf(v[1], sc, sh), 0.f);
    o0.z = fmaxf(fmaf(v[2], sc, sh), 0.f);
    o0.w = fmaxf(fmaf(v[3], sc, sh), 0.f);
    o1.x = fmaxf(fmaf(v[4], sc, sh), 0.f);
    o1.y = fmaxf(fmaf(v[5], sc, sh), 0.f);
    o1.z = fmaxf(fmaf(v[6], sc, sh), 0.f);
    o1.w = fmaxf(fmaf(v[7], sc, sh), 0.f);
    *(float4*)(out + i8) = o0;
    *(float4*)(out + i8 + 4) = o1;
}

extern "C" void kernel_launch(void* const* d_in, const int* in_sizes, int n_in,
                              void* d_out, int out_size, void* d_ws, size_t ws_size,
                              hipStream_t stream) {
    const float* x     = (const float*)d_in[0];
    const float* lin_w = (const float*)d_in[1];
    // d_in[2] = lin_b: a per-channel constant shift of conv output, which
    // BatchNorm subtracts back out exactly (mean shifts identically) -> unused.
    const float* gamma = (const float*)d_in[3];
    const float* beta  = (const float*)d_in[4];
    float* out = (float*)d_out;

    float* stats = (float*)d_ws;                                  // 16 floats
    __hip_bfloat16* ws_y = (__hip_bfloat16*)((char*)d_ws + 256);  // conv output, bf16

    const size_t n_elem = (size_t)BATCH * COUT * HH * WW;         // 33,554,432
    const size_t need = 256 + n_elem * 2;

    hipMemsetAsync(d_ws, 0, 256, stream);  // zero stats (ws is re-poisoned 0xAA)

    dim3 grid(WW / 256, HH / TPX, BATCH);
    if (ws_size >= need) {
        conv_kernel<0><<<grid, 256, 0, stream>>>(x, lin_w, gamma, beta, ws_y, stats, out);
        bn_kernel<<<(unsigned)(n_elem / (8 * 256)), 256, 0, stream>>>(ws_y, stats, gamma, beta, out);
    } else {
        conv_kernel<1><<<grid, 256, 0, stream>>>(x, lin_w, gamma, beta, ws_y, stats, out);
        conv_kernel<2><<<grid, 256, 0, stream>>>(x, lin_w, gamma, beta, ws_y, stats, out);
    }
}